// Round 3
// baseline (55.101 us; speedup 1.0000x reference)
//
#include <hip/hip_runtime.h>

// MSCA fused multi-scale depthwise conv chain. TWO (b,c) planes per workgroup:
// each wave interleaves two independent plane-chains (ILP latency hiding),
// barriers amortized over 2x work. x:[8,256,64,64] f32 -> 3 outputs same shape.
//
// LDS per plane: R1 (68x68: X padded +-2 -> A0Y -> A2Y), R2 (64x68: ATT -> A1Y).
// Total 2*(4624+4352) = 17952 words = 71808 B -> 2 blocks/CU.
// Horizontal halos via DPP lane shifts, vertical halos via guarded reads.

#define YS 68
#define R1W 4624   // 68*68
#define R2W 4352   // 64*68
#define LDS_WORDS (2 * (R1W + R2W))

__device__ __forceinline__ float dpp_prev(float v) {   // lane i <- lane i-1
    return __int_as_float(__builtin_amdgcn_update_dpp(
        0, __float_as_int(v), 0x111, 0xF, 0xF, false));  // row_shr:1
}
__device__ __forceinline__ float dpp_next(float v) {   // lane i <- lane i+1
    return __int_as_float(__builtin_amdgcn_update_dpp(
        0, __float_as_int(v), 0x101, 0xF, 0xF, false));  // row_shl:1
}
__device__ __forceinline__ void ld4(const float* p, float* f) {
    float4 q = *(const float4*)p;
    f[0] = q.x; f[1] = q.y; f[2] = q.z; f[3] = q.w;
}
__device__ __forceinline__ void st4(float* p, float a, float b, float c, float d) {
    float4 q; q.x = a; q.y = b; q.z = c; q.w = d;
    *(float4*)p = q;
}

__global__ __launch_bounds__(256, 2)
void msca_fused(const float* __restrict__ x,
                const float* __restrict__ w0,   const float* __restrict__ b0,
                const float* __restrict__ w0_1, const float* __restrict__ b0_1,
                const float* __restrict__ w0_2, const float* __restrict__ b0_2,
                const float* __restrict__ w1_1, const float* __restrict__ b1_1,
                const float* __restrict__ w1_2, const float* __restrict__ b1_2,
                const float* __restrict__ w2_1, const float* __restrict__ b2_1,
                const float* __restrict__ w2_2, const float* __restrict__ b2_2,
                float* __restrict__ out)
{
    __shared__ __align__(16) float lds[LDS_WORDS];

    const int t  = threadIdx.x;
    const int r  = t >> 2;          // row-mapped: image row
    const int jg = t & 3;           // col-group
    const int j0 = jg << 4;
    const int c  = t & 63;          // col-mapped: column
    const int i0 = (t >> 6) << 4;   // col-mapped: first of 16 rows

    const int plane0 = blockIdx.x * 2;

    float xR[2][16], attnR[2][16], a0xR[2][16], a0yR[2][16];
    float a1xR[2][16], a1yR[2][16], a2xR[2][16];

    // ---- stage 0: global loads, zero halos, commit x ----
    #pragma unroll
    for (int p = 0; p < 2; p++) {
        const float* xg = x + (size_t)(plane0 + p) * 4096;
        #pragma unroll
        for (int k = 0; k < 4; k++) ld4(&xg[r * 64 + j0 + 4 * k], &xR[p][4 * k]);
    }
    #pragma unroll
    for (int p = 0; p < 2; p++) {
        float* R1p = lds + p * R1W;
        #pragma unroll
        for (int k0 = 0; k0 < 2; k0++) {
            int k = t + 256 * k0;
            if (k < 272) R1p[k < 136 ? k : k + 4352] = 0.f;   // halo rows 0,1,66,67
        }
        if (t < 64) {
            int b = (t + 2) * YS;
            R1p[b] = 0.f; R1p[b + 1] = 0.f; R1p[b + 66] = 0.f; R1p[b + 67] = 0.f;
        }
        float* row = &R1p[(r + 2) * YS];
        float2 e0; e0.x = xR[p][0];  e0.y = xR[p][1];  *(float2*)&row[j0 + 2]  = e0;
        st4(&row[j0 + 4],  xR[p][2],  xR[p][3],  xR[p][4],  xR[p][5]);
        st4(&row[j0 + 8],  xR[p][6],  xR[p][7],  xR[p][8],  xR[p][9]);
        st4(&row[j0 + 12], xR[p][10], xR[p][11], xR[p][12], xR[p][13]);
        float2 e1; e1.x = xR[p][14]; e1.y = xR[p][15]; *(float2*)&row[j0 + 16] = e1;
    }
    __syncthreads();   // B1

    // ---- P1: attn = conv5x5(x)+b0 (row-mapped; center row regs+DPP) ----
    #pragma unroll
    for (int p = 0; p < 2; p++) {
        const int ch = (plane0 + p) & 255;
        float* R1p = lds + p * R1W;
        float* R2p = lds + 2 * R1W + p * R2W;
        const float bb = b0[ch];
        #pragma unroll
        for (int j = 0; j < 16; j++) attnR[p][j] = bb;
        #pragma unroll
        for (int dr = 0; dr < 5; dr++) {
            float f[20];
            if (dr == 2) {
                float e0 = dpp_prev(xR[p][14]), e1 = dpp_prev(xR[p][15]);
                float e2 = dpp_next(xR[p][0]),  e3 = dpp_next(xR[p][1]);
                f[0] = jg ? e0 : 0.f;  f[1] = jg ? e1 : 0.f;
                #pragma unroll
                for (int k = 0; k < 16; k++) f[2 + k] = xR[p][k];
                f[18] = (jg < 3) ? e2 : 0.f;  f[19] = (jg < 3) ? e3 : 0.f;
            } else {
                const float* row = &R1p[(r + dr) * YS + j0];
                #pragma unroll
                for (int k = 0; k < 5; k++) ld4(&row[4 * k], &f[4 * k]);
            }
            #pragma unroll
            for (int v = 0; v < 5; v++) {
                const float ww = w0[ch * 25 + dr * 5 + v];
                #pragma unroll
                for (int j = 0; j < 16; j++) attnR[p][j] += ww * f[j + v];
            }
        }
        float* row = &R2p[r * YS];
        st4(&row[j0],      attnR[p][0],  attnR[p][1],  attnR[p][2],  attnR[p][3]);
        st4(&row[j0 + 4],  attnR[p][4],  attnR[p][5],  attnR[p][6],  attnR[p][7]);
        st4(&row[j0 + 8],  attnR[p][8],  attnR[p][9],  attnR[p][10], attnR[p][11]);
        st4(&row[j0 + 12], attnR[p][12], attnR[p][13], attnR[p][14], attnR[p][15]);
    }
    __syncthreads();   // B2

    // ---- P2: a0x (regs+DPP), a0y (col-mapped guarded) ----
    #pragma unroll
    for (int p = 0; p < 2; p++) {
        const int ch = (plane0 + p) & 255;
        const float bb = b0_1[ch];
        float av[22];
        float p13 = dpp_prev(attnR[p][13]), p14 = dpp_prev(attnR[p][14]), p15 = dpp_prev(attnR[p][15]);
        float n0  = dpp_next(attnR[p][0]),  n1  = dpp_next(attnR[p][1]),  n2  = dpp_next(attnR[p][2]);
        av[0] = jg ? p13 : 0.f;  av[1] = jg ? p14 : 0.f;  av[2] = jg ? p15 : 0.f;
        #pragma unroll
        for (int k = 0; k < 16; k++) av[3 + k] = attnR[p][k];
        av[19] = (jg < 3) ? n0 : 0.f;  av[20] = (jg < 3) ? n1 : 0.f;  av[21] = (jg < 3) ? n2 : 0.f;
        #pragma unroll
        for (int j = 0; j < 16; j++) a0xR[p][j] = bb;
        #pragma unroll
        for (int v = 0; v < 7; v++) {
            const float ww = w0_1[ch * 7 + v];
            #pragma unroll
            for (int j = 0; j < 16; j++) a0xR[p][j] += ww * av[j + v];
        }
    }
    #pragma unroll
    for (int p = 0; p < 2; p++) {
        const int ch = (plane0 + p) & 255;
        float* R1p = lds + p * R1W;
        float* R2p = lds + 2 * R1W + p * R2W;
        const float bb = b0_2[ch];
        float cv[22];
        #pragma unroll
        for (int d = 0; d < 22; d++) {
            const int ir = i0 + d - 3;
            cv[d] = ((unsigned)ir <= 63u) ? R2p[ir * YS + c] : 0.f;
        }
        #pragma unroll
        for (int ii = 0; ii < 16; ii++) a0yR[p][ii] = bb;
        #pragma unroll
        for (int u = 0; u < 7; u++) {
            const float ww = w0_2[ch * 7 + u];
            #pragma unroll
            for (int ii = 0; ii < 16; ii++) a0yR[p][ii] += ww * cv[ii + u];
        }
        #pragma unroll
        for (int ii = 0; ii < 16; ii++) R1p[(i0 + ii) * YS + c] = a0yR[p][ii];   // A0Y
    }
    __syncthreads();   // B3

    // ---- P3: store attn_0; a1x (regs+DPP); a1y (col guarded) ----
    #pragma unroll
    for (int p = 0; p < 2; p++) {
        float* R1p = lds + p * R1W;
        float* o0 = out + (size_t)(plane0 + p) * 4096;
        #pragma unroll
        for (int k = 0; k < 4; k++) {
            float f[4]; ld4(&R1p[r * YS + j0 + 4 * k], f);
            st4(&o0[r * 64 + j0 + 4 * k],
                a0xR[p][4 * k] * f[0], a0xR[p][4 * k + 1] * f[1],
                a0xR[p][4 * k + 2] * f[2], a0xR[p][4 * k + 3] * f[3]);
        }
    }
    #pragma unroll
    for (int p = 0; p < 2; p++) {
        const int ch = (plane0 + p) & 255;
        const float bb = b1_1[ch];
        float xv[26];
        #pragma unroll
        for (int d = 0; d < 5; d++) {
            float pp = dpp_prev(a0xR[p][11 + d]);
            float nn = dpp_next(a0xR[p][d]);
            xv[d]      = jg ? pp : 0.f;
            xv[21 + d] = (jg < 3) ? nn : 0.f;
        }
        #pragma unroll
        for (int k = 0; k < 16; k++) xv[5 + k] = a0xR[p][k];
        #pragma unroll
        for (int j = 0; j < 16; j++) a1xR[p][j] = bb;
        #pragma unroll
        for (int v = 0; v < 11; v++) {
            const float ww = w1_1[ch * 11 + v];
            #pragma unroll
            for (int j = 0; j < 16; j++) a1xR[p][j] += ww * xv[j + v];
        }
    }
    #pragma unroll
    for (int p = 0; p < 2; p++) {
        const int ch = (plane0 + p) & 255;
        float* R1p = lds + p * R1W;
        float* R2p = lds + 2 * R1W + p * R2W;
        const float bb = b1_2[ch];
        float yv[26];
        #pragma unroll
        for (int d = 0; d < 5; d++)  yv[d]      = i0        ? R1p[(i0 - 5 + d) * YS + c]  : 0.f;
        #pragma unroll
        for (int k = 0; k < 16; k++) yv[5 + k]  = a0yR[p][k];
        #pragma unroll
        for (int d = 0; d < 5; d++)  yv[21 + d] = (i0 < 48) ? R1p[(i0 + 16 + d) * YS + c] : 0.f;
        #pragma unroll
        for (int ii = 0; ii < 16; ii++) a1yR[p][ii] = bb;
        #pragma unroll
        for (int u = 0; u < 11; u++) {
            const float ww = w1_2[ch * 11 + u];
            #pragma unroll
            for (int ii = 0; ii < 16; ii++) a1yR[p][ii] += ww * yv[ii + u];
        }
        #pragma unroll
        for (int ii = 0; ii < 16; ii++) R2p[(i0 + ii) * YS + c] = a1yR[p][ii];   // A1Y
    }
    __syncthreads();   // B4

    // ---- P4: store attn_1; a2x (regs+DPP); a2y (col guarded) ----
    #pragma unroll
    for (int p = 0; p < 2; p++) {
        float* R2p = lds + 2 * R1W + p * R2W;
        float* o1 = out + 8388608 + (size_t)(plane0 + p) * 4096;
        #pragma unroll
        for (int k = 0; k < 4; k++) {
            float f[4]; ld4(&R2p[r * YS + j0 + 4 * k], f);
            st4(&o1[r * 64 + j0 + 4 * k],
                a1xR[p][4 * k] * f[0], a1xR[p][4 * k + 1] * f[1],
                a1xR[p][4 * k + 2] * f[2], a1xR[p][4 * k + 3] * f[3]);
        }
    }
    #pragma unroll
    for (int p = 0; p < 2; p++) {
        const int ch = (plane0 + p) & 255;
        const float bb = b2_1[ch];
        float xv[36];
        #pragma unroll
        for (int d = 0; d < 10; d++) {
            float pp = dpp_prev(a1xR[p][6 + d]);
            float nn = dpp_next(a1xR[p][d]);
            xv[d]      = jg ? pp : 0.f;
            xv[26 + d] = (jg < 3) ? nn : 0.f;
        }
        #pragma unroll
        for (int k = 0; k < 16; k++) xv[10 + k] = a1xR[p][k];
        #pragma unroll
        for (int j = 0; j < 16; j++) a2xR[p][j] = bb;
        #pragma unroll
        for (int v = 0; v < 21; v++) {
            const float ww = w2_1[ch * 21 + v];
            #pragma unroll
            for (int j = 0; j < 16; j++) a2xR[p][j] += ww * xv[j + v];
        }
    }
    #pragma unroll
    for (int p = 0; p < 2; p++) {
        const int ch = (plane0 + p) & 255;
        float* R1p = lds + p * R1W;
        float* R2p = lds + 2 * R1W + p * R2W;
        const float bb = b2_2[ch];
        float yv[36];
        #pragma unroll
        for (int d = 0; d < 10; d++) yv[d]      = i0        ? R2p[(i0 - 10 + d) * YS + c] : 0.f;
        #pragma unroll
        for (int k = 0; k < 16; k++) yv[10 + k] = a1yR[p][k];
        #pragma unroll
        for (int d = 0; d < 10; d++) yv[26 + d] = (i0 < 48) ? R2p[(i0 + 16 + d) * YS + c] : 0.f;
        float a2y[16];
        #pragma unroll
        for (int ii = 0; ii < 16; ii++) a2y[ii] = bb;
        #pragma unroll
        for (int u = 0; u < 21; u++) {
            const float ww = w2_2[ch * 21 + u];
            #pragma unroll
            for (int ii = 0; ii < 16; ii++) a2y[ii] += ww * yv[ii + u];
        }
        #pragma unroll
        for (int ii = 0; ii < 16; ii++) R1p[(i0 + ii) * YS + c] = a2y[ii];   // A2Y
    }
    __syncthreads();   // B5

    // ---- P5: store attn_2 = a2x * a2y ----
    #pragma unroll
    for (int p = 0; p < 2; p++) {
        float* R1p = lds + p * R1W;
        float* o2 = out + 2 * 8388608 + (size_t)(plane0 + p) * 4096;
        #pragma unroll
        for (int k = 0; k < 4; k++) {
            float f[4]; ld4(&R1p[r * YS + j0 + 4 * k], f);
            st4(&o2[r * 64 + j0 + 4 * k],
                a2xR[p][4 * k] * f[0], a2xR[p][4 * k + 1] * f[1],
                a2xR[p][4 * k + 2] * f[2], a2xR[p][4 * k + 3] * f[3]);
        }
    }
}

extern "C" void kernel_launch(void* const* d_in, const int* in_sizes, int n_in,
                              void* d_out, int out_size, void* d_ws, size_t ws_size,
                              hipStream_t stream) {
    msca_fused<<<1024, 256, 0, stream>>>(
        (const float*)d_in[0],
        (const float*)d_in[1],  (const float*)d_in[2],
        (const float*)d_in[3],  (const float*)d_in[4],
        (const float*)d_in[5],  (const float*)d_in[6],
        (const float*)d_in[7],  (const float*)d_in[8],
        (const float*)d_in[9],  (const float*)d_in[10],
        (const float*)d_in[11], (const float*)d_in[12],
        (const float*)d_in[13], (const float*)d_in[14],
        (float*)d_out);
}

// Round 4
// 49.661 us; speedup vs baseline: 1.1095x; 1.1095x over previous
//
#include <hip/hip_runtime.h>

// MSCA fused multi-scale depthwise conv chain, one workgroup per (b,c) plane.
// x:[8,256,64,64] f32 -> (attn_0, attn_1, attn_2) each [8,256,64,64] f32.
//
// R3: R1-structure (1 plane/block, 36KB LDS, 16 waves/CU) +
//  (a) float2 packed FMA (v_pk_fma_f32 on even-parity taps),
//  (b) deferred product stores: o0 issued at start of P4, o1/o2 after last
//      barrier -> no __syncthreads waits on a fresh global store.
// LDS: R1 region (68x68: X padded +-2 -> A0Y -> A2Y), R2 (64x68: ATT -> A1Y).

#define YS 68
#define R1W 4624   // 68*68
#define R2W 4352   // 64*68
#define LDS_WORDS (R1W + R2W)

typedef float v2f __attribute__((ext_vector_type(2)));

__device__ __forceinline__ float dpp_prev(float v) {   // lane i <- lane i-1
    return __int_as_float(__builtin_amdgcn_update_dpp(
        0, __float_as_int(v), 0x111, 0xF, 0xF, false));  // row_shr:1
}
__device__ __forceinline__ float dpp_next(float v) {   // lane i <- lane i+1
    return __int_as_float(__builtin_amdgcn_update_dpp(
        0, __float_as_int(v), 0x101, 0xF, 0xF, false));  // row_shl:1
}
__device__ __forceinline__ void ld4p(const float* p, v2f* w) {  // -> 2 pairs
    float4 q = *(const float4*)p;
    w[0].x = q.x; w[0].y = q.y; w[1].x = q.z; w[1].y = q.w;
}
__device__ __forceinline__ void st4p(float* p, v2f a, v2f b) {
    float4 q; q.x = a.x; q.y = a.y; q.z = b.x; q.w = b.y;
    *(float4*)p = q;
}

// Packed conv accumulate: logical window f[i] = wnd[i/2].{x,y}, f[0] at even
// offset from outputs. Output j=2k+{0,1}: A[k] += wt[v] * f[j + v + TAPOFF].
template<int K, int TAPOFF>
__device__ __forceinline__ void conv_acc(const float* __restrict__ wrow,
                                         const v2f* wnd, v2f* A) {
    #pragma unroll
    for (int v = 0; v < K; v++) {
        const float w = wrow[v];
        const int u = v + TAPOFF;
        if ((u & 1) == 0) {
            v2f wv; wv.x = w; wv.y = w;
            #pragma unroll
            for (int k = 0; k < 8; k++) A[k] += wv * wnd[(u >> 1) + k];
        } else {
            #pragma unroll
            for (int k = 0; k < 8; k++) {
                A[k].x += w * wnd[(u >> 1) + k].y;
                A[k].y += w * wnd[(u >> 1) + k + 1].x;
            }
        }
    }
}

__global__ __launch_bounds__(256, 4)
void msca_fused(const float* __restrict__ x,
                const float* __restrict__ w0,   const float* __restrict__ b0,
                const float* __restrict__ w0_1, const float* __restrict__ b0_1,
                const float* __restrict__ w0_2, const float* __restrict__ b0_2,
                const float* __restrict__ w1_1, const float* __restrict__ b1_1,
                const float* __restrict__ w1_2, const float* __restrict__ b1_2,
                const float* __restrict__ w2_1, const float* __restrict__ b2_1,
                const float* __restrict__ w2_2, const float* __restrict__ b2_2,
                float* __restrict__ out)
{
    __shared__ __align__(16) float lds[LDS_WORDS];
    float* R1 = lds;            // X (padded +-2) -> A0Y -> A2Y
    float* R2 = lds + R1W;      // ATT -> A1Y

    const int t  = threadIdx.x;
    const int r  = t >> 2;          // row-mapped: image row
    const int jg = t & 3;
    const int j0 = jg << 4;
    const int c  = t & 63;          // col-mapped: column
    const int i0 = (t >> 6) << 4;   // col-mapped: first of 16 rows (uniform/wave)

    const int plane = blockIdx.x;
    const int ch    = plane & 255;

    const float* xg = x + (size_t)plane * 4096;
    float* o0 = out + (size_t)plane * 4096;
    float* o1 = o0 + 8388608;
    float* o2 = o1 + 8388608;

    // ---- stage 0: load x, zero halos, commit to LDS ----
    v2f xR2[8];
    #pragma unroll
    for (int m = 0; m < 4; m++) ld4p(&xg[r * 64 + j0 + 4 * m], &xR2[2 * m]);

    #pragma unroll
    for (int k0 = 0; k0 < 2; k0++) {
        int k = t + 256 * k0;
        if (k < 272) R1[k < 136 ? k : k + 4352] = 0.f;   // halo rows 0,1,66,67
    }
    if (t < 64) {
        int b = (t + 2) * YS;
        R1[b] = 0.f; R1[b + 1] = 0.f; R1[b + 66] = 0.f; R1[b + 67] = 0.f;
    }
    {
        float* row = &R1[(r + 2) * YS];
        row[j0 + 2] = xR2[0].x;  row[j0 + 3] = xR2[0].y;
        st4p(&row[j0 + 4],  xR2[1], xR2[2]);
        st4p(&row[j0 + 8],  xR2[3], xR2[4]);
        st4p(&row[j0 + 12], xR2[5], xR2[6]);
        row[j0 + 16] = xR2[7].x; row[j0 + 17] = xR2[7].y;
    }
    __syncthreads();   // B1

    // ---- P1: attn = conv5x5(x)+b0 (row-mapped; center row regs+DPP) ----
    v2f attn2[8];
    {
        const float bb = b0[ch];
        #pragma unroll
        for (int k = 0; k < 8; k++) { attn2[k].x = bb; attn2[k].y = bb; }
        #pragma unroll
        for (int dr = 0; dr < 5; dr++) {
            v2f wnd[10];
            if (dr == 2) {
                float e0 = dpp_prev(xR2[7].x), e1 = dpp_prev(xR2[7].y);
                float n0 = dpp_next(xR2[0].x), n1 = dpp_next(xR2[0].y);
                wnd[0].x = jg ? e0 : 0.f;  wnd[0].y = jg ? e1 : 0.f;
                #pragma unroll
                for (int k = 0; k < 8; k++) wnd[1 + k] = xR2[k];
                wnd[9].x = (jg < 3) ? n0 : 0.f;  wnd[9].y = (jg < 3) ? n1 : 0.f;
            } else {
                const float* row = &R1[(r + dr) * YS + j0];
                #pragma unroll
                for (int m = 0; m < 5; m++) ld4p(&row[4 * m], &wnd[2 * m]);
            }
            conv_acc<5, 0>(w0 + ch * 25 + dr * 5, wnd, attn2);
        }
        float* row = &R2[r * YS];
        st4p(&row[j0],      attn2[0], attn2[1]);
        st4p(&row[j0 + 4],  attn2[2], attn2[3]);
        st4p(&row[j0 + 8],  attn2[4], attn2[5]);
        st4p(&row[j0 + 12], attn2[6], attn2[7]);
    }
    __syncthreads();   // B2 (ATT ready; X read done -> R1 free)

    // ---- P2a: a0x = conv1x7(attn)+b0_1 (regs+DPP; window start -4) ----
    v2f a0x2[8];
    {
        const float bb = b0_1[ch];
        #pragma unroll
        for (int k = 0; k < 8; k++) { a0x2[k].x = bb; a0x2[k].y = bb; }
        v2f wnd[12];
        float p13 = dpp_prev(attn2[6].y), p14 = dpp_prev(attn2[7].x), p15 = dpp_prev(attn2[7].y);
        float n0 = dpp_next(attn2[0].x), n1 = dpp_next(attn2[0].y), n2 = dpp_next(attn2[1].x);
        wnd[0].x = 0.f;               wnd[0].y = jg ? p13 : 0.f;
        wnd[1].x = jg ? p14 : 0.f;    wnd[1].y = jg ? p15 : 0.f;
        #pragma unroll
        for (int k = 0; k < 8; k++) wnd[2 + k] = attn2[k];
        wnd[10].x = (jg < 3) ? n0 : 0.f;  wnd[10].y = (jg < 3) ? n1 : 0.f;
        wnd[11].x = (jg < 3) ? n2 : 0.f;  wnd[11].y = 0.f;
        conv_acc<7, 1>(w0_1 + ch * 7, wnd, a0x2);
    }
    // ---- P2b: a0y = conv7x1(attn)+b0_2 (col-mapped; window start -4) ----
    v2f a0y2[8];
    {
        const float bb = b0_2[ch];
        #pragma unroll
        for (int k = 0; k < 8; k++) { a0y2[k].x = bb; a0y2[k].y = bb; }
        v2f wnd[12];
        #define GATT(ir) (((unsigned)(ir) <= 63u) ? R2[(ir) * YS + c] : 0.f)
        wnd[0].x = 0.f;             wnd[0].y = GATT(i0 - 3);
        wnd[1].x = GATT(i0 - 2);    wnd[1].y = GATT(i0 - 1);
        #pragma unroll
        for (int m = 0; m < 8; m++) {
            wnd[2 + m].x = R2[(i0 + 2 * m) * YS + c];
            wnd[2 + m].y = R2[(i0 + 2 * m + 1) * YS + c];
        }
        wnd[10].x = GATT(i0 + 16);  wnd[10].y = GATT(i0 + 17);
        wnd[11].x = GATT(i0 + 18);  wnd[11].y = 0.f;
        #undef GATT
        conv_acc<7, 1>(w0_2 + ch * 7, wnd, a0y2);
        #pragma unroll
        for (int m = 0; m < 8; m++) {
            R1[(i0 + 2 * m) * YS + c]     = a0y2[m].x;   // A0Y
            R1[(i0 + 2 * m + 1) * YS + c] = a0y2[m].y;
        }
    }
    __syncthreads();   // B3 (A0Y ready; ATT read done -> R2 free)

    // ---- P3: prod0 = a0x*A0Y (regs); a1x (regs+DPP); a1y (col) ----
    v2f prod0[8];
    #pragma unroll
    for (int m = 0; m < 4; m++) {
        v2f p[2]; ld4p(&R1[r * YS + j0 + 4 * m], p);
        prod0[2 * m]     = a0x2[2 * m] * p[0];
        prod0[2 * m + 1] = a0x2[2 * m + 1] * p[1];
    }
    v2f a1x2[8];
    {
        const float bb = b1_1[ch];
        #pragma unroll
        for (int k = 0; k < 8; k++) { a1x2[k].x = bb; a1x2[k].y = bb; }
        v2f wnd[14];
        float p11 = dpp_prev(a0x2[5].y), p12 = dpp_prev(a0x2[6].x), p13 = dpp_prev(a0x2[6].y);
        float p14 = dpp_prev(a0x2[7].x), p15 = dpp_prev(a0x2[7].y);
        float n0 = dpp_next(a0x2[0].x), n1 = dpp_next(a0x2[0].y), n2 = dpp_next(a0x2[1].x);
        float n3 = dpp_next(a0x2[1].y), n4 = dpp_next(a0x2[2].x);
        wnd[0].x = 0.f;             wnd[0].y = jg ? p11 : 0.f;
        wnd[1].x = jg ? p12 : 0.f;  wnd[1].y = jg ? p13 : 0.f;
        wnd[2].x = jg ? p14 : 0.f;  wnd[2].y = jg ? p15 : 0.f;
        #pragma unroll
        for (int k = 0; k < 8; k++) wnd[3 + k] = a0x2[k];
        wnd[11].x = (jg < 3) ? n0 : 0.f;  wnd[11].y = (jg < 3) ? n1 : 0.f;
        wnd[12].x = (jg < 3) ? n2 : 0.f;  wnd[12].y = (jg < 3) ? n3 : 0.f;
        wnd[13].x = (jg < 3) ? n4 : 0.f;  wnd[13].y = 0.f;
        conv_acc<11, 1>(w1_1 + ch * 11, wnd, a1x2);
    }
    v2f a1y2[8];
    {
        const float bb = b1_2[ch];
        #pragma unroll
        for (int k = 0; k < 8; k++) { a1y2[k].x = bb; a1y2[k].y = bb; }
        v2f wnd[14];
        #define GA0Y(ir) (((unsigned)(ir) <= 63u) ? R1[(ir) * YS + c] : 0.f)
        wnd[0].x = 0.f;             wnd[0].y = GA0Y(i0 - 5);
        wnd[1].x = GA0Y(i0 - 4);    wnd[1].y = GA0Y(i0 - 3);
        wnd[2].x = GA0Y(i0 - 2);    wnd[2].y = GA0Y(i0 - 1);
        #pragma unroll
        for (int k = 0; k < 8; k++) wnd[3 + k] = a0y2[k];
        wnd[11].x = GA0Y(i0 + 16);  wnd[11].y = GA0Y(i0 + 17);
        wnd[12].x = GA0Y(i0 + 18);  wnd[12].y = GA0Y(i0 + 19);
        wnd[13].x = GA0Y(i0 + 20);  wnd[13].y = 0.f;
        #undef GA0Y
        conv_acc<11, 1>(w1_2 + ch * 11, wnd, a1y2);
        #pragma unroll
        for (int m = 0; m < 8; m++) {
            R2[(i0 + 2 * m) * YS + c]     = a1y2[m].x;   // A1Y
            R2[(i0 + 2 * m + 1) * YS + c] = a1y2[m].y;
        }
    }
    __syncthreads();   // B4 (A1Y ready; A0Y read done -> R1 free)

    // ---- P4: store o0 (drains during this phase); prod1; a2x; a2y ----
    st4p(&o0[r * 64 + j0],      prod0[0], prod0[1]);
    st4p(&o0[r * 64 + j0 + 4],  prod0[2], prod0[3]);
    st4p(&o0[r * 64 + j0 + 8],  prod0[4], prod0[5]);
    st4p(&o0[r * 64 + j0 + 12], prod0[6], prod0[7]);

    v2f prod1[8];
    #pragma unroll
    for (int m = 0; m < 4; m++) {
        v2f p[2]; ld4p(&R2[r * YS + j0 + 4 * m], p);
        prod1[2 * m]     = a1x2[2 * m] * p[0];
        prod1[2 * m + 1] = a1x2[2 * m + 1] * p[1];
    }
    v2f a2x2[8];
    {
        const float bb = b2_1[ch];
        #pragma unroll
        for (int k = 0; k < 8; k++) { a2x2[k].x = bb; a2x2[k].y = bb; }
        v2f wnd[18];
        float pv[10], nv[10];
        #pragma unroll
        for (int d = 0; d < 10; d++) {
            // pv[d] = col j0-10+d = prev strip col 6+d ; a1xR[6+d]
            int q = 6 + d;
            float pe = dpp_prev((q & 1) ? a1x2[q >> 1].y : a1x2[q >> 1].x);
            float ne = dpp_next((d & 1) ? a1x2[d >> 1].y : a1x2[d >> 1].x);
            pv[d] = jg ? pe : 0.f;
            nv[d] = (jg < 3) ? ne : 0.f;
        }
        #pragma unroll
        for (int m = 0; m < 5; m++) { wnd[m].x = pv[2 * m]; wnd[m].y = pv[2 * m + 1]; }
        #pragma unroll
        for (int k = 0; k < 8; k++) wnd[5 + k] = a1x2[k];
        #pragma unroll
        for (int m = 0; m < 5; m++) { wnd[13 + m].x = nv[2 * m]; wnd[13 + m].y = nv[2 * m + 1]; }
        conv_acc<21, 0>(w2_1 + ch * 21, wnd, a2x2);
    }
    {
        const float bb = b2_2[ch];
        v2f a2y2[8];
        #pragma unroll
        for (int k = 0; k < 8; k++) { a2y2[k].x = bb; a2y2[k].y = bb; }
        v2f wnd[18];
        #define GA1Y(ir) (((unsigned)(ir) <= 63u) ? R2[(ir) * YS + c] : 0.f)
        #pragma unroll
        for (int m = 0; m < 5; m++) {
            wnd[m].x = GA1Y(i0 - 10 + 2 * m);  wnd[m].y = GA1Y(i0 - 9 + 2 * m);
        }
        #pragma unroll
        for (int k = 0; k < 8; k++) wnd[5 + k] = a1y2[k];
        #pragma unroll
        for (int m = 0; m < 5; m++) {
            wnd[13 + m].x = GA1Y(i0 + 16 + 2 * m);  wnd[13 + m].y = GA1Y(i0 + 17 + 2 * m);
        }
        #undef GA1Y
        conv_acc<21, 0>(w2_2 + ch * 21, wnd, a2y2);
        #pragma unroll
        for (int m = 0; m < 8; m++) {
            R1[(i0 + 2 * m) * YS + c]     = a2y2[m].x;   // A2Y
            R1[(i0 + 2 * m + 1) * YS + c] = a2y2[m].y;
        }
    }
    __syncthreads();   // B5 (A2Y ready; o0 stores long drained)

    // ---- P5: store o1; prod2 = a2x*A2Y; store o2 ----
    st4p(&o1[r * 64 + j0],      prod1[0], prod1[1]);
    st4p(&o1[r * 64 + j0 + 4],  prod1[2], prod1[3]);
    st4p(&o1[r * 64 + j0 + 8],  prod1[4], prod1[5]);
    st4p(&o1[r * 64 + j0 + 12], prod1[6], prod1[7]);
    #pragma unroll
    for (int m = 0; m < 4; m++) {
        v2f p[2]; ld4p(&R1[r * YS + j0 + 4 * m], p);
        v2f q0 = a2x2[2 * m] * p[0];
        v2f q1 = a2x2[2 * m + 1] * p[1];
        st4p(&o2[r * 64 + j0 + 4 * m], q0, q1);
    }
}

extern "C" void kernel_launch(void* const* d_in, const int* in_sizes, int n_in,
                              void* d_out, int out_size, void* d_ws, size_t ws_size,
                              hipStream_t stream) {
    msca_fused<<<2048, 256, 0, stream>>>(
        (const float*)d_in[0],
        (const float*)d_in[1],  (const float*)d_in[2],
        (const float*)d_in[3],  (const float*)d_in[4],
        (const float*)d_in[5],  (const float*)d_in[6],
        (const float*)d_in[7],  (const float*)d_in[8],
        (const float*)d_in[9],  (const float*)d_in[10],
        (const float*)d_in[11], (const float*)d_in[12],
        (const float*)d_in[13], (const float*)d_in[14],
        (float*)d_out);
}

// Round 7
// 47.218 us; speedup vs baseline: 1.1669x; 1.0517x over previous
//
#include <hip/hip_runtime.h>

// MSCA fused multi-scale depthwise conv chain, one workgroup per (b,c) plane.
// x:[8,256,64,64] f32 -> (attn_0, attn_1, attn_2) each [8,256,64,64] f32.
//
// R6 = R5 + DPP-hoist fix in build_twnd. DPP cross-lane ops are convergent;
// they must execute unconditionally (all lanes active), with the jg-boundary
// select applied AFTERWARD (v_cndmask), never `jg ? dpp(...) : 0`. The
// inside-ternary form let the compiler exec-mask the source lanes at strip
// seams, zeroing halos (R4/R5 failures, out0 err ~3e-2 at 16-row seams).
//
// Layouts (elementary): RB: ATT_T [col*68+row] -> Y1 [row*68+col]
//                       RA: X (68x68 +-2 halo) -> Y0 [row*68+col] -> Y2 [row*68+col]
// x-chain packed f2 (R3-proven); y-chain scalar T-space windows w/ DPP halos.
// 5 barriers; o0 stored at start of P4, o1/o2 in P5 (drain under compute).

#define RA_W 4624                  // 68*68
#define RB_W 4352                  // 64*68
#define LDS_WORDS (RA_W + RB_W)    // 8976 words = 35904 B -> 4 blocks/CU

typedef float v2f __attribute__((ext_vector_type(2)));

__device__ __forceinline__ float dpp_prev(float v) {   // lane i <- lane i-1
    return __int_as_float(__builtin_amdgcn_update_dpp(
        0, __float_as_int(v), 0x111, 0xF, 0xF, false));  // row_shr:1
}
__device__ __forceinline__ float dpp_next(float v) {   // lane i <- lane i+1
    return __int_as_float(__builtin_amdgcn_update_dpp(
        0, __float_as_int(v), 0x101, 0xF, 0xF, false));  // row_shl:1
}
__device__ __forceinline__ void ld4p(const float* p, v2f* w) {
    float4 q = *(const float4*)p;
    w[0].x = q.x; w[0].y = q.y; w[1].x = q.z; w[1].y = q.w;
}
__device__ __forceinline__ void st4p(float* p, v2f a, v2f b) {
    float4 q; q.x = a.x; q.y = a.y; q.z = b.x; q.w = b.y;
    *(float4*)p = q;
}
__device__ __forceinline__ float elem(const v2f* a, int e) {
    return (e & 1) ? a[e >> 1].y : a[e >> 1].x;
}

// Packed conv (R3-proven): window f[i] = wnd[i/2].{x,y}; out j=2k+{0,1}:
// A[k] += wt[v] * f[j + v + TAPOFF].
template<int K, int TAPOFF>
__device__ __forceinline__ void conv_acc(const float* __restrict__ wrow,
                                         const v2f* wnd, v2f* A) {
    #pragma unroll
    for (int v = 0; v < K; v++) {
        const float w = wrow[v];
        const int u = v + TAPOFF;
        if ((u & 1) == 0) {
            v2f wv; wv.x = w; wv.y = w;
            #pragma unroll
            for (int k = 0; k < 8; k++) A[k] += wv * wnd[(u >> 1) + k];
        } else {
            #pragma unroll
            for (int k = 0; k < 8; k++) {
                A[k].x += w * wnd[(u >> 1) + k].y;
                A[k].y += w * wnd[(u >> 1) + k + 1].x;
            }
        }
    }
}

// Scalar T-space window: s[16] = strip rows j0..j0+15 (one column);
// w[d] = row j0-H+d. DPPs hoisted UNCONDITIONALLY (convergent), select after.
template<int H>
__device__ __forceinline__ void build_twnd(const float* s, float* w, int jg) {
    float pv[H], nv[H];
    #pragma unroll
    for (int d = 0; d < H; d++) pv[d] = dpp_prev(s[16 - H + d]);
    #pragma unroll
    for (int d = 0; d < H; d++) nv[d] = dpp_next(s[d]);
    #pragma unroll
    for (int d = 0; d < H; d++) w[d] = jg ? pv[d] : 0.f;
    #pragma unroll
    for (int k = 0; k < 16; k++) w[H + k] = s[k];
    #pragma unroll
    for (int d = 0; d < H; d++) w[H + 16 + d] = (jg < 3) ? nv[d] : 0.f;
}
// acc[k] = bb + sum_u wt[u] * w[k+u]   (K = 2H+1 taps, centered)
template<int K>
__device__ __forceinline__ void conv_t(const float* __restrict__ wrow,
                                       const float* w, float bb, float* acc) {
    #pragma unroll
    for (int k = 0; k < 16; k++) acc[k] = bb;
    #pragma unroll
    for (int u = 0; u < K; u++) {
        const float ww = wrow[u];
        #pragma unroll
        for (int k = 0; k < 16; k++) acc[k] += ww * w[k + u];
    }
}

__global__ __launch_bounds__(256, 4)
void msca_fused(const float* __restrict__ x,
                const float* __restrict__ w0,   const float* __restrict__ b0,
                const float* __restrict__ w0_1, const float* __restrict__ b0_1,
                const float* __restrict__ w0_2, const float* __restrict__ b0_2,
                const float* __restrict__ w1_1, const float* __restrict__ b1_1,
                const float* __restrict__ w1_2, const float* __restrict__ b1_2,
                const float* __restrict__ w2_1, const float* __restrict__ b2_1,
                const float* __restrict__ w2_2, const float* __restrict__ b2_2,
                float* __restrict__ out)
{
    __shared__ __align__(16) float lds[LDS_WORDS];
    float* RA = lds;            // X (68x68, +-2 halo) -> Y0 -> Y2
    float* RB = lds + RA_W;     // ATT_T -> Y1

    const int t  = threadIdx.x;
    const int r  = t >> 2;          // row-mapped: image row; T-mapped: image col
    const int jg = t & 3;
    const int j0 = jg << 4;

    const int plane = blockIdx.x;
    const int ch    = plane & 255;

    const float* xg = x + (size_t)plane * 4096;
    float* o0 = out + (size_t)plane * 4096;
    float* o1 = o0 + 8388608;
    float* o2 = o1 + 8388608;

    // ---- stage 0: load x, zero X halos, commit to LDS (R3-proven) ----
    v2f xR2[8];
    #pragma unroll
    for (int m = 0; m < 4; m++) ld4p(&xg[r * 64 + j0 + 4 * m], &xR2[2 * m]);

    #pragma unroll
    for (int k0 = 0; k0 < 2; k0++) {
        int k = t + 256 * k0;
        if (k < 272) RA[k < 136 ? k : k + 4352] = 0.f;   // X halo rows 0,1,66,67
    }
    if (t < 64) {
        int b = (t + 2) * 68;
        RA[b] = 0.f; RA[b + 1] = 0.f; RA[b + 66] = 0.f; RA[b + 67] = 0.f;
    }
    {
        float* row = &RA[(r + 2) * 68];
        row[j0 + 2] = xR2[0].x;  row[j0 + 3] = xR2[0].y;
        st4p(&row[j0 + 4],  xR2[1], xR2[2]);
        st4p(&row[j0 + 8],  xR2[3], xR2[4]);
        st4p(&row[j0 + 12], xR2[5], xR2[6]);
        row[j0 + 16] = xR2[7].x; row[j0 + 17] = xR2[7].y;
    }
    __syncthreads();   // B1

    // ---- P1: attn = conv5x5(x)+b0 (R3-proven); scatter ATT_T [col*68+row] ----
    v2f attn2[8];
    {
        const float bb = b0[ch];
        #pragma unroll
        for (int k = 0; k < 8; k++) { attn2[k].x = bb; attn2[k].y = bb; }
        #pragma unroll
        for (int dr = 0; dr < 5; dr++) {
            v2f wnd[10];
            if (dr == 2) {
                float e0 = dpp_prev(xR2[7].x), e1 = dpp_prev(xR2[7].y);
                float n0 = dpp_next(xR2[0].x), n1 = dpp_next(xR2[0].y);
                wnd[0].x = jg ? e0 : 0.f;  wnd[0].y = jg ? e1 : 0.f;
                #pragma unroll
                for (int k = 0; k < 8; k++) wnd[1 + k] = xR2[k];
                wnd[9].x = (jg < 3) ? n0 : 0.f;  wnd[9].y = (jg < 3) ? n1 : 0.f;
            } else {
                const float* row = &RA[(r + dr) * 68 + j0];
                #pragma unroll
                for (int m = 0; m < 5; m++) ld4p(&row[4 * m], &wnd[2 * m]);
            }
            conv_acc<5, 0>(w0 + ch * 25 + dr * 5, wnd, attn2);
        }
        #pragma unroll
        for (int e = 0; e < 16; e++) RB[(j0 + e) * 68 + r] = elem(attn2, e);
    }
    __syncthreads();   // B2  (ATT_T ready; X reads done)

    // ---- P2: a0x (R3-proven); T-strip read; a0y scalar; scatter Y0 ----
    v2f a0x2[8];
    {
        const float bb = b0_1[ch];
        #pragma unroll
        for (int k = 0; k < 8; k++) { a0x2[k].x = bb; a0x2[k].y = bb; }
        v2f wnd[12];
        float p13 = dpp_prev(attn2[6].y), p14 = dpp_prev(attn2[7].x), p15 = dpp_prev(attn2[7].y);
        float n0 = dpp_next(attn2[0].x), n1 = dpp_next(attn2[0].y), n2 = dpp_next(attn2[1].x);
        wnd[0].x = 0.f;               wnd[0].y = jg ? p13 : 0.f;
        wnd[1].x = jg ? p14 : 0.f;    wnd[1].y = jg ? p15 : 0.f;
        #pragma unroll
        for (int k = 0; k < 8; k++) wnd[2 + k] = attn2[k];
        wnd[10].x = (jg < 3) ? n0 : 0.f;  wnd[10].y = (jg < 3) ? n1 : 0.f;
        wnd[11].x = (jg < 3) ? n2 : 0.f;  wnd[11].y = 0.f;
        conv_acc<7, 1>(w0_1 + ch * 7, wnd, a0x2);
    }
    float sT[16];     // attn(rows j0..j0+15, col r)
    #pragma unroll
    for (int m = 0; m < 4; m++) {
        float4 q = *(const float4*)&RB[r * 68 + j0 + 4 * m];
        sT[4 * m] = q.x; sT[4 * m + 1] = q.y; sT[4 * m + 2] = q.z; sT[4 * m + 3] = q.w;
    }
    float a0y[16];
    {
        float w[22];
        build_twnd<3>(sT, w, jg);
        conv_t<7>(w0_2 + ch * 7, w, b0_2[ch], a0y);
        #pragma unroll
        for (int e = 0; e < 16; e++) RA[(j0 + e) * 68 + r] = a0y[e];   // Y0[row*68+col]
    }
    __syncthreads();   // B3  (Y0 ready; ATT_T reads done)

    // ---- P3: prod0 = a0x * Y0; a1x (R3-proven); a1y scalar; scatter Y1 ----
    v2f prod0[8];
    #pragma unroll
    for (int m = 0; m < 4; m++) {
        v2f p[2]; ld4p(&RA[r * 68 + j0 + 4 * m], p);
        prod0[2 * m]     = a0x2[2 * m] * p[0];
        prod0[2 * m + 1] = a0x2[2 * m + 1] * p[1];
    }
    v2f a1x2[8];
    {
        const float bb = b1_1[ch];
        #pragma unroll
        for (int k = 0; k < 8; k++) { a1x2[k].x = bb; a1x2[k].y = bb; }
        v2f wnd[14];
        float p11 = dpp_prev(a0x2[5].y), p12 = dpp_prev(a0x2[6].x), p13 = dpp_prev(a0x2[6].y);
        float p14 = dpp_prev(a0x2[7].x), p15 = dpp_prev(a0x2[7].y);
        float n0 = dpp_next(a0x2[0].x), n1 = dpp_next(a0x2[0].y), n2 = dpp_next(a0x2[1].x);
        float n3 = dpp_next(a0x2[1].y), n4 = dpp_next(a0x2[2].x);
        wnd[0].x = 0.f;             wnd[0].y = jg ? p11 : 0.f;
        wnd[1].x = jg ? p12 : 0.f;  wnd[1].y = jg ? p13 : 0.f;
        wnd[2].x = jg ? p14 : 0.f;  wnd[2].y = jg ? p15 : 0.f;
        #pragma unroll
        for (int k = 0; k < 8; k++) wnd[3 + k] = a0x2[k];
        wnd[11].x = (jg < 3) ? n0 : 0.f;  wnd[11].y = (jg < 3) ? n1 : 0.f;
        wnd[12].x = (jg < 3) ? n2 : 0.f;  wnd[12].y = (jg < 3) ? n3 : 0.f;
        wnd[13].x = (jg < 3) ? n4 : 0.f;  wnd[13].y = 0.f;
        conv_acc<11, 1>(w1_1 + ch * 11, wnd, a1x2);
    }
    float a1y[16];
    {
        float w[26];
        build_twnd<5>(a0y, w, jg);
        conv_t<11>(w1_2 + ch * 11, w, b1_2[ch], a1y);
        #pragma unroll
        for (int e = 0; e < 16; e++) RB[(j0 + e) * 68 + r] = a1y[e];   // Y1[row*68+col]
    }
    __syncthreads();   // B4  (Y1 ready; Y0 reads done)

    // ---- P4: store o0; prod1 = a1x * Y1; a2x (R3-proven); a2y; scatter Y2 ----
    st4p(&o0[r * 64 + j0],      prod0[0], prod0[1]);
    st4p(&o0[r * 64 + j0 + 4],  prod0[2], prod0[3]);
    st4p(&o0[r * 64 + j0 + 8],  prod0[4], prod0[5]);
    st4p(&o0[r * 64 + j0 + 12], prod0[6], prod0[7]);

    v2f prod1[8];
    #pragma unroll
    for (int m = 0; m < 4; m++) {
        v2f p[2]; ld4p(&RB[r * 68 + j0 + 4 * m], p);
        prod1[2 * m]     = a1x2[2 * m] * p[0];
        prod1[2 * m + 1] = a1x2[2 * m + 1] * p[1];
    }
    v2f a2x2[8];
    {
        const float bb = b2_1[ch];
        #pragma unroll
        for (int k = 0; k < 8; k++) { a2x2[k].x = bb; a2x2[k].y = bb; }
        v2f wnd[18];
        float pv[10], nv[10];
        #pragma unroll
        for (int d = 0; d < 10; d++) {
            int q = 6 + d;
            float pe = dpp_prev((q & 1) ? a1x2[q >> 1].y : a1x2[q >> 1].x);
            float ne = dpp_next((d & 1) ? a1x2[d >> 1].y : a1x2[d >> 1].x);
            pv[d] = jg ? pe : 0.f;
            nv[d] = (jg < 3) ? ne : 0.f;
        }
        #pragma unroll
        for (int m = 0; m < 5; m++) { wnd[m].x = pv[2 * m]; wnd[m].y = pv[2 * m + 1]; }
        #pragma unroll
        for (int k = 0; k < 8; k++) wnd[5 + k] = a1x2[k];
        #pragma unroll
        for (int m = 0; m < 5; m++) { wnd[13 + m].x = nv[2 * m]; wnd[13 + m].y = nv[2 * m + 1]; }
        conv_acc<21, 0>(w2_1 + ch * 21, wnd, a2x2);
    }
    {
        float w[36], a2y[16];
        build_twnd<10>(a1y, w, jg);
        conv_t<21>(w2_2 + ch * 21, w, b2_2[ch], a2y);
        #pragma unroll
        for (int e = 0; e < 16; e++) RA[(j0 + e) * 68 + r] = a2y[e];   // Y2[row*68+col]
    }
    __syncthreads();   // B5  (Y2 ready; o0 drained under P4 compute)

    // ---- P5: store o1; prod2 = a2x * Y2; store o2 ----
    st4p(&o1[r * 64 + j0],      prod1[0], prod1[1]);
    st4p(&o1[r * 64 + j0 + 4],  prod1[2], prod1[3]);
    st4p(&o1[r * 64 + j0 + 8],  prod1[4], prod1[5]);
    st4p(&o1[r * 64 + j0 + 12], prod1[6], prod1[7]);
    #pragma unroll
    for (int m = 0; m < 4; m++) {
        v2f p[2]; ld4p(&RA[r * 68 + j0 + 4 * m], p);
        v2f q0 = a2x2[2 * m] * p[0];
        v2f q1 = a2x2[2 * m + 1] * p[1];
        st4p(&o2[r * 64 + j0 + 4 * m], q0, q1);
    }
}

extern "C" void kernel_launch(void* const* d_in, const int* in_sizes, int n_in,
                              void* d_out, int out_size, void* d_ws, size_t ws_size,
                              hipStream_t stream) {
    msca_fused<<<2048, 256, 0, stream>>>(
        (const float*)d_in[0],
        (const float*)d_in[1],  (const float*)d_in[2],
        (const float*)d_in[3],  (const float*)d_in[4],
        (const float*)d_in[5],  (const float*)d_in[6],
        (const float*)d_in[7],  (const float*)d_in[8],
        (const float*)d_in[9],  (const float*)d_in[10],
        (const float*)d_in[11], (const float*)d_in[12],
        (const float*)d_in[13], (const float*)d_in[14],
        (float*)d_out);
}

// Round 8
// 44.849 us; speedup vs baseline: 1.2286x; 1.0528x over previous
//
#include <hip/hip_runtime.h>

// MSCA fused multi-scale depthwise conv chain, one workgroup per (b,c) plane.
// x:[8,256,64,64] f32 -> (attn_0, attn_1, attn_2) each [8,256,64,64] f32.
//
// R7: 512 threads/block, 8 px/thread, 36KB LDS -> 4 blocks/CU = 32 waves/CU
// (needs VGPR<=64). Strips of 8; halos via DPP row_shr/shl 1,2 (hoisted, then
// selected -- R6 lesson); 8-lane strip seams == image edges, so masks align.
// X-role: row=maj, cols [8*lane8,+8). T-role: col=maj, rows [8*lane8,+8).
// Transpose layouts use involution swizzle: minor' = minor ^ (strip<<3):
//   write:  buf[(8*lane8+e)*68 + (maj ^ (lane8<<3))]
//   read :  buf[maj*68 + ((lane8 ^ ((maj>>3)&7))<<3) + e]   (2x b128, aligned)
// -> all scatters <=2-way bank conflict; all strip reads b128.
// Liveness: RA: X(68x68,+-2 halo) -> Y0 -> Y2 ; RB: ATT_T -> Y1. 5 barriers.
// o0 stored at start of P4, o1/o2 in P5 (drain under compute).

#define RA_W 4624                  // 68*68
#define RB_W 4352                  // 64*68
#define LDS_WORDS (RA_W + RB_W)    // 8976 words = 35904 B

__device__ __forceinline__ float dppsr1(float v) {   // lane i <- i-1 (16-lane rows)
    return __int_as_float(__builtin_amdgcn_update_dpp(
        0, __float_as_int(v), 0x111, 0xF, 0xF, false));
}
__device__ __forceinline__ float dppsr2(float v) {   // lane i <- i-2
    return __int_as_float(__builtin_amdgcn_update_dpp(
        0, __float_as_int(v), 0x112, 0xF, 0xF, false));
}
__device__ __forceinline__ float dppsl1(float v) {   // lane i <- i+1
    return __int_as_float(__builtin_amdgcn_update_dpp(
        0, __float_as_int(v), 0x101, 0xF, 0xF, false));
}
__device__ __forceinline__ float dppsl2(float v) {   // lane i <- i+2
    return __int_as_float(__builtin_amdgcn_update_dpp(
        0, __float_as_int(v), 0x102, 0xF, 0xF, false));
}
__device__ __forceinline__ void ld8(const float* p, float* d) {
    float4 a = *(const float4*)p, b = *(const float4*)(p + 4);
    d[0]=a.x; d[1]=a.y; d[2]=a.z; d[3]=a.w; d[4]=b.x; d[5]=b.y; d[6]=b.z; d[7]=b.w;
}
__device__ __forceinline__ void st8(float* p, const float* d) {
    float4 a, b;
    a.x=d[0]; a.y=d[1]; a.z=d[2]; a.w=d[3]; b.x=d[4]; b.y=d[5]; b.z=d[6]; b.w=d[7];
    *(float4*)p = a; *(float4*)(p + 4) = b;
}

// Accumulate window part: src[i] sits at window position W0+i (N elements).
// acc[j] += wt[v]*window[j+v] for all in-range terms. All indices static.
template<int K, int W0, int N>
__device__ __forceinline__ void cpart(const float* __restrict__ wt,
                                      const float* s, float* acc) {
    #pragma unroll
    for (int v = 0; v < K; v++) {
        #pragma unroll
        for (int j = 0; j < 8; j++) {
            const int p = j + v - W0;
            if (p >= 0 && p < N) acc[j] += wt[v] * s[p];
        }
    }
}

// Strip conv, K=2H+1 taps, H<=8: halo from lane+-1 (DPP hoisted, select after).
template<int H>
__device__ __forceinline__ void sconv(const float* __restrict__ wt, float bb,
                                      const float* a, bool pm, bool np, float* acc) {
    constexpr int K = 2 * H + 1;
    float pv[H], nv[H];
    #pragma unroll
    for (int i = 0; i < H; i++) pv[i] = dppsr1(a[8 - H + i]);
    #pragma unroll
    for (int i = 0; i < H; i++) nv[i] = dppsl1(a[i]);
    #pragma unroll
    for (int i = 0; i < H; i++) pv[i] = pm ? pv[i] : 0.f;
    #pragma unroll
    for (int i = 0; i < H; i++) nv[i] = np ? nv[i] : 0.f;
    #pragma unroll
    for (int j = 0; j < 8; j++) acc[j] = bb;
    cpart<K, 0, H>(wt, pv, acc);
    cpart<K, H, 8>(wt, a, acc);
    cpart<K, H + 8, H>(wt, nv, acc);
}

// 21-tap strip conv (H=10): halo spans lane+-1 (8) and lane+-2 (2).
__device__ __forceinline__ void sconv21(const float* __restrict__ wt, float bb,
                                        const float* a, bool pm, bool pm2,
                                        bool np, bool np2, float* acc) {
    #pragma unroll
    for (int j = 0; j < 8; j++) acc[j] = bb;
    {
        float q[2];
        q[0] = dppsr2(a[6]); q[1] = dppsr2(a[7]);
        q[0] = pm2 ? q[0] : 0.f; q[1] = pm2 ? q[1] : 0.f;
        cpart<21, 0, 2>(wt, q, acc);
    }
    {
        float pv[8];
        #pragma unroll
        for (int i = 0; i < 8; i++) pv[i] = dppsr1(a[i]);
        #pragma unroll
        for (int i = 0; i < 8; i++) pv[i] = pm ? pv[i] : 0.f;
        cpart<21, 2, 8>(wt, pv, acc);
    }
    cpart<21, 10, 8>(wt, a, acc);
    {
        float nv[8];
        #pragma unroll
        for (int i = 0; i < 8; i++) nv[i] = dppsl1(a[i]);
        #pragma unroll
        for (int i = 0; i < 8; i++) nv[i] = np ? nv[i] : 0.f;
        cpart<21, 18, 8>(wt, nv, acc);
    }
    {
        float q[2];
        q[0] = dppsl2(a[0]); q[1] = dppsl2(a[1]);
        q[0] = np2 ? q[0] : 0.f; q[1] = np2 ? q[1] : 0.f;
        cpart<21, 26, 2>(wt, q, acc);
    }
}

__global__ __launch_bounds__(512, 8)
void msca_fused(const float* __restrict__ x,
                const float* __restrict__ w0,   const float* __restrict__ b0,
                const float* __restrict__ w0_1, const float* __restrict__ b0_1,
                const float* __restrict__ w0_2, const float* __restrict__ b0_2,
                const float* __restrict__ w1_1, const float* __restrict__ b1_1,
                const float* __restrict__ w1_2, const float* __restrict__ b1_2,
                const float* __restrict__ w2_1, const float* __restrict__ b2_1,
                const float* __restrict__ w2_2, const float* __restrict__ b2_2,
                float* __restrict__ out)
{
    __shared__ __align__(16) float lds[LDS_WORDS];
    float* RA = lds;            // X (68x68, +-2 halo) -> Y0 -> Y2
    float* RB = lds + RA_W;     // ATT_T -> Y1

    const int t     = threadIdx.x;     // 0..511
    const int maj   = t >> 3;          // X: image row r ; T: image col c
    const int lane8 = t & 7;           // X: col-strip jg ; T: row-strip s
    const int j0    = lane8 << 3;

    const bool pm  = lane8 >= 1, np  = lane8 <= 6;
    const bool pm2 = lane8 >= 2, np2 = lane8 <= 5;

    const int scat = maj ^ (lane8 << 3);                     // scatter minor
    const int rdb  = maj * 68 + ((lane8 ^ ((maj >> 3) & 7)) << 3); // strip read base

    const int plane = blockIdx.x;
    const int ch    = plane & 255;

    const float* xg = x + (size_t)plane * 4096;
    float* o0 = out + (size_t)plane * 4096;
    float* o1 = o0 + 8388608;
    float* o2 = o1 + 8388608;

    // ---- stage 0: load x (8 px), zero X halos, commit ----
    float xr[8];
    ld8(&xg[maj * 64 + j0], xr);
    if (t < 136) { RA[t] = 0.f; RA[t + 4488] = 0.f; }        // halo rows 0,1,66,67
    if (t < 256) {                                            // side cols rows 2..65
        int rr = 2 + (t >> 2), cc = t & 3;
        RA[rr * 68 + (cc < 2 ? cc : cc + 64)] = 0.f;
    }
    {
        float* row = &RA[(maj + 2) * 68 + j0 + 2];
        float2 p;
        p.x = xr[0]; p.y = xr[1]; ((float2*)row)[0] = p;
        p.x = xr[2]; p.y = xr[3]; ((float2*)row)[1] = p;
        p.x = xr[4]; p.y = xr[5]; ((float2*)row)[2] = p;
        p.x = xr[6]; p.y = xr[7]; ((float2*)row)[3] = p;
    }
    __syncthreads();   // B1

    // ---- P1: attn = conv5x5(x)+b0 (all rows from LDS); scatter ATT_T ----
    float attn[8];
    {
        const float bb = b0[ch];
        #pragma unroll
        for (int j = 0; j < 8; j++) attn[j] = bb;
        const float* w0p = w0 + ch * 25;
        #pragma unroll
        for (int dr = 0; dr < 5; dr++) {
            float wnd[12];                      // image cols j0-2 .. j0+9
            const float* rowp = &RA[(maj + dr) * 68 + j0];
            float4 qa = *(const float4*)rowp;
            float4 qb = *(const float4*)(rowp + 4);
            float4 qc = *(const float4*)(rowp + 8);
            wnd[0]=qa.x; wnd[1]=qa.y; wnd[2]=qa.z;  wnd[3]=qa.w;
            wnd[4]=qb.x; wnd[5]=qb.y; wnd[6]=qb.z;  wnd[7]=qb.w;
            wnd[8]=qc.x; wnd[9]=qc.y; wnd[10]=qc.z; wnd[11]=qc.w;
            #pragma unroll
            for (int v = 0; v < 5; v++) {
                const float ww = w0p[dr * 5 + v];
                #pragma unroll
                for (int j = 0; j < 8; j++) attn[j] += ww * wnd[j + v];
            }
        }
        #pragma unroll
        for (int e = 0; e < 8; e++) RB[(j0 + e) * 68 + scat] = attn[e];
    }
    __syncthreads();   // B2  (ATT_T ready; X reads done)

    // ---- P2: a0x (X-role); read attn T-strip; a0y (T-role); scatter Y0 ----
    float a0x[8];
    sconv<3>(w0_1 + ch * 7, b0_1[ch], attn, pm, np, a0x);
    float stv[8];
    ld8(&RB[rdb], stv);
    float aty0[8];
    sconv<3>(w0_2 + ch * 7, b0_2[ch], stv, pm, np, aty0);   // s-masks == lane8-masks
    #pragma unroll
    for (int d = 0; d < 8; d++) RA[(j0 + d) * 68 + scat] = aty0[d];   // Y0
    __syncthreads();   // B3  (Y0 ready; ATT_T reads done)

    // ---- P3: prod0 = a0x*Y0row; a1x; a1y (T); scatter Y1 ----
    float prod0[8];
    {
        float y0r[8];
        ld8(&RA[rdb], y0r);
        #pragma unroll
        for (int j = 0; j < 8; j++) prod0[j] = a0x[j] * y0r[j];
    }
    float a1x[8];
    sconv<5>(w1_1 + ch * 11, b1_1[ch], a0x, pm, np, a1x);
    float aty1[8];
    sconv<5>(w1_2 + ch * 11, b1_2[ch], aty0, pm, np, aty1);
    #pragma unroll
    for (int d = 0; d < 8; d++) RB[(j0 + d) * 68 + scat] = aty1[d];   // Y1
    __syncthreads();   // B4  (Y1 ready; Y0 reads done)

    // ---- P4: store o0; prod1 = a1x*Y1row; a2y (T) -> Y2; a2x ----
    st8(&o0[maj * 64 + j0], prod0);
    float prod1[8];
    {
        float y1r[8];
        ld8(&RB[rdb], y1r);
        #pragma unroll
        for (int j = 0; j < 8; j++) prod1[j] = a1x[j] * y1r[j];
    }
    {
        float a2y[8];
        sconv21(w2_2 + ch * 21, b2_2[ch], aty1, pm, pm2, np, np2, a2y);
        #pragma unroll
        for (int d = 0; d < 8; d++) RA[(j0 + d) * 68 + scat] = a2y[d]; // Y2
    }
    float a2x[8];
    sconv21(w2_1 + ch * 21, b2_1[ch], a1x, pm, pm2, np, np2, a2x);
    __syncthreads();   // B5  (Y2 ready; o0 drained under P4 compute)

    // ---- P5: store o1; prod2 = a2x*Y2row; store o2 ----
    st8(&o1[maj * 64 + j0], prod1);
    {
        float y2r[8], prod2[8];
        ld8(&RA[rdb], y2r);
        #pragma unroll
        for (int j = 0; j < 8; j++) prod2[j] = a2x[j] * y2r[j];
        st8(&o2[maj * 64 + j0], prod2);
    }
}

extern "C" void kernel_launch(void* const* d_in, const int* in_sizes, int n_in,
                              void* d_out, int out_size, void* d_ws, size_t ws_size,
                              hipStream_t stream) {
    msca_fused<<<2048, 512, 0, stream>>>(
        (const float*)d_in[0],
        (const float*)d_in[1],  (const float*)d_in[2],
        (const float*)d_in[3],  (const float*)d_in[4],
        (const float*)d_in[5],  (const float*)d_in[6],
        (const float*)d_in[7],  (const float*)d_in[8],
        (const float*)d_in[9],  (const float*)d_in[10],
        (const float*)d_in[11], (const float*)d_in[12],
        (const float*)d_in[13], (const float*)d_in[14],
        (float*)d_out);
}